// Round 12
// baseline (149.800 us; speedup 1.0000x reference)
//
#include <hip/hip_runtime.h>

constexpr int EMB_DIM   = 300;
constexpr int HIDDEN    = 256;
constexpr int OUT_DIM   = 3;
constexpr int SEQ       = 128;
constexpr int N_ASPECTS = 8;
constexpr int TILE      = 32;    // bucket padding granularity
constexpr int MTILE     = 8;     // samples per MLP block (2 groups x 4)

// ---------------------------------------------------------------------------
// bf16 helpers (RNE)
// ---------------------------------------------------------------------------
__device__ __forceinline__ unsigned int bfbits(float f) {
  unsigned int u = __float_as_uint(f);
  return (u + 0x7fffu + ((u >> 16) & 1u)) >> 16;
}
__device__ __forceinline__ unsigned int pack2(float lo, float hi) {
  return bfbits(lo) | (bfbits(hi) << 16);
}
__device__ __forceinline__ float blo(unsigned int u) { return __uint_as_float(u << 16); }
__device__ __forceinline__ float bhi(unsigned int u) { return __uint_as_float(u & 0xffff0000u); }

// ---------------------------------------------------------------------------
// Fused prep: block 0 = deterministic counting-sort bucketing (pad to TILE,
// -1 = padding); blocks 1..N = fp32->bf16 table conversion (90 MB stream),
// unified 600B rows (R6/R10 best-measured layout).
// ---------------------------------------------------------------------------
__global__ __launch_bounds__(1024) void prep_kernel(
    const float* __restrict__ emb, unsigned int* __restrict__ emb16, int n8,
    const int* __restrict__ aspect, int B, int* __restrict__ perm, int nperm) {
  const int t = threadIdx.x;

  if (blockIdx.x != 0) {
    int i = (blockIdx.x - 1) * 1024 + t;
    const int stride = (gridDim.x - 1) * 1024;
    for (; i < n8; i += stride) {
      const float4* p = (const float4*)emb + (size_t)i * 2;
      float4 a = p[0], b = p[1];
      uint4 o;
      o.x = pack2(a.x, a.y); o.y = pack2(a.z, a.w);
      o.z = pack2(b.x, b.y); o.w = pack2(b.z, b.w);
      ((uint4*)emb16)[i] = o;
    }
    return;
  }

  const int lane = t & 63, wave = t >> 6;          // 16 waves
  __shared__ int wcnt[16][N_ASPECTS];
  __shared__ int cur[16][N_ASPECTS];

  for (int i = t; i < nperm; i += 1024) perm[i] = -1;

  int my_a[8];
  int cnt[N_ASPECTS];
#pragma unroll
  for (int q = 0; q < N_ASPECTS; ++q) cnt[q] = 0;
#pragma unroll
  for (int k = 0; k < 8; ++k) {
    int s = t + k * 1024;
    int a = (s < B) ? aspect[s] : -1;
    my_a[k] = a;
#pragma unroll
    for (int q = 0; q < N_ASPECTS; ++q) cnt[q] += (a == q);
  }
#pragma unroll
  for (int q = 0; q < N_ASPECTS; ++q) {
    int c = cnt[q];
    for (int off = 32; off > 0; off >>= 1) c += __shfl_down(c, off);
    if (lane == 0) wcnt[wave][q] = c;
  }
  __syncthreads();
  if (t == 0) {
    int base = 0;
    for (int q = 0; q < N_ASPECTS; ++q) {
      int tot = 0;
      for (int w = 0; w < 16; ++w) { cur[w][q] = base + tot; tot += wcnt[w][q]; }
      base += ((tot + TILE - 1) / TILE) * TILE;
    }
  }
  __syncthreads();

#pragma unroll
  for (int k = 0; k < 8; ++k) {
    int a = my_a[k];
    int s = t + k * 1024;
#pragma unroll
    for (int q = 0; q < N_ASPECTS; ++q) {
      unsigned long long m = __ballot(a == q);
      if (a == q) {
        int rank = __popcll(m & ((1ull << lane) - 1ull));
        int pos = cur[wave][q] + rank;
        perm[pos] = s;
        if (rank == __popcll(m) - 1) cur[wave][q] = pos + 1;
      }
    }
  }
}

// ---------------------------------------------------------------------------
// Pool (R10 layout, deeper pipeline): one sample per wave; bitonic-sorted ids
// -> vocab-sweep convoy. Inner loop = explicit 8-token two-phase pipeline:
// issue 16 loads (8x uint2 A + 8x masked uint2 B) back-to-back, THEN
// accumulate -- doubles memory-level parallelism vs R10's unroll-4
// (VGPR 16 -> ~56). All array indices static after unroll (rule #20).
// ---------------------------------------------------------------------------
__global__ __launch_bounds__(256) void pool_kernel(
    const int* __restrict__ ids, const unsigned short* __restrict__ emb16,
    float* __restrict__ x, int B) {
  const int wave = threadIdx.x >> 6, lane = threadIdx.x & 63;
  const int b = blockIdx.x * 4 + wave;
  if (b >= B) return;

  int r0 = ids[(size_t)b * SEQ + lane];
  int r1 = ids[(size_t)b * SEQ + lane + 64];

  // bitonic sort of 128 ids (regs+shfl); sort bugs can only cost locality
#pragma unroll
  for (int k = 2; k <= 128; k <<= 1) {
#pragma unroll
    for (int j = k >> 1; j >= 1; j >>= 1) {
      if (j == 64) {
        int lo = min(r0, r1), hi = max(r0, r1);
        r0 = lo; r1 = hi;
      } else {
        const bool up0 = ((lane & k) == 0);
        const bool up1 = (((lane + 64) & k) == 0);
        const bool side = ((lane & j) == 0);
        int o0 = __shfl_xor(r0, j);
        int o1 = __shfl_xor(r1, j);
        r0 = (side == up0) ? min(r0, o0) : max(r0, o0);
        r1 = (side == up1) ? min(r1, o1) : max(r1, o1);
      }
    }
  }

  // wave-local LDS byte offsets (id*600); no barrier needed (same-wave RAW)
  __shared__ int sOff[4][SEQ];
  sOff[wave][lane]      = r0 * (EMB_DIM * 2);
  sOff[wave][lane + 64] = r1 * (EMB_DIM * 2);

  const char* __restrict__ pA = (const char*)emb16 + (size_t)lane * 8;
  const char* __restrict__ pB = (const char*)emb16 + 512 + (size_t)lane * 8;
  const bool tail = (lane < 11);

  float a0 = 0.f, a1 = 0.f, a2 = 0.f, a3 = 0.f;
  float c0 = 0.f, c1 = 0.f, c2 = 0.f, c3 = 0.f;

  for (int s = 0; s < SEQ; s += 8) {
    uint2 va[8], vb[8];
    // phase 1: issue all 16 loads back-to-back (8 full-wave A + 8 masked B)
#pragma unroll
    for (int k = 0; k < 8; ++k) {
      const int off = sOff[wave][s + k];
      va[k] = *(const uint2*)(pA + off);
      if (tail) vb[k] = *(const uint2*)(pB + off);
    }
    // phase 2: accumulate
#pragma unroll
    for (int k = 0; k < 8; ++k) {
      a0 += blo(va[k].x); a1 += bhi(va[k].x);
      a2 += blo(va[k].y); a3 += bhi(va[k].y);
    }
    if (tail) {
#pragma unroll
      for (int k = 0; k < 8; ++k) {
        c0 += blo(vb[k].x); c1 += bhi(vb[k].x);
        c2 += blo(vb[k].y); c3 += bhi(vb[k].y);
      }
    }
  }

  const float sc = 1.0f / (float)SEQ;
  float4* __restrict__ xr = (float4*)(x + (size_t)b * EMB_DIM);
  xr[lane] = make_float4(a0 * sc, a1 * sc, a2 * sc, a3 * sc);
  if (tail)
    xr[64 + lane] = make_float4(c0 * sc, c1 * sc, c2 * sc, c3 * sc);
}

// ---------------------------------------------------------------------------
// Routed MLP, split-K, MTILE=8 (R10 form: 4 blocks/CU -> 4 waves/SIMD).
// All register-array indices compile-time static (rule #20).
// ---------------------------------------------------------------------------
__global__ __launch_bounds__(256) void mlp_kernel(
    const float* __restrict__ x, const int* __restrict__ aspect,
    const int* __restrict__ perm,
    const float* __restrict__ W1, const float* __restrict__ b1,
    const float* __restrict__ W2, const float* __restrict__ b2,
    float* __restrict__ out) {
  const int t = threadIdx.x;
  const int wave = t >> 6, lane = t & 63;
  const int g = wave >> 1;                 // sample group 0/1
  const int kw = wave & 1;                 // K-half
  const int start = blockIdx.x * MTILE;

  __shared__ int ss[MTILE];
  __shared__ float xch[2][4][64][4];       // partner-half partials, 8 KB

  if (t < MTILE) ss[t] = perm[start + t];
  __syncthreads();
  const int s0 = ss[0];
  if (s0 < 0) return;                      // fully-padded block (uniform exit)
  const int a = aspect[s0];

  int smp[4];
  const float* xrow[4];
#pragma unroll
  for (int s = 0; s < 4; ++s) {
    int m = __builtin_amdgcn_readfirstlane(ss[g * 4 + s]);
    smp[s] = m;
    xrow[s] = x + (size_t)(m < 0 ? s0 : m) * EMB_DIM;
  }

  const float4* __restrict__ w1r =
      (const float4*)(W1 + (size_t)a * EMB_DIM * HIDDEN) + lane;
  float4 acc[4];
  if (kw == 0) {
    const float4 bb = ((const float4*)(b1 + a * HIDDEN))[lane];
#pragma unroll
    for (int s = 0; s < 4; ++s) acc[s] = bb;
  } else {
#pragma unroll
    for (int s = 0; s < 4; ++s) acc[s] = make_float4(0.f, 0.f, 0.f, 0.f);
  }
  const int d0 = kw ? 160 : 0;
  const int d1 = kw ? EMB_DIM : 160;
#pragma unroll 2
  for (int d = d0; d < d1; d += 4) {
    float4 xv[4];
#pragma unroll
    for (int s = 0; s < 4; ++s) xv[s] = *(const float4*)(xrow[s] + d);
#pragma unroll
    for (int dd = 0; dd < 4; ++dd) {
      const float4 w = w1r[(size_t)(d + dd) * (HIDDEN / 4)];
#pragma unroll
      for (int s = 0; s < 4; ++s) {
        const float xs = dd == 0 ? xv[s].x : dd == 1 ? xv[s].y
                        : dd == 2 ? xv[s].z : xv[s].w;
        acc[s].x = fmaf(xs, w.x, acc[s].x);
        acc[s].y = fmaf(xs, w.y, acc[s].y);
        acc[s].z = fmaf(xs, w.z, acc[s].z);
        acc[s].w = fmaf(xs, w.w, acc[s].w);
      }
    }
  }

  if (kw == 0) {
    *(float4*)&xch[g][2][lane][0] = acc[2];
    *(float4*)&xch[g][3][lane][0] = acc[3];
  } else {
    *(float4*)&xch[g][0][lane][0] = acc[0];
    *(float4*)&xch[g][1][lane][0] = acc[1];
  }
  __syncthreads();

  const float4* __restrict__ w2p =
      (const float4*)(W2 + (size_t)a * HIDDEN * OUT_DIM + lane * 12);
  const float4 w2a = w2p[0];   // j0k0 j0k1 j0k2 j1k0
  const float4 w2b = w2p[1];   // j1k1 j1k2 j2k0 j2k1
  const float4 w2c = w2p[2];   // j2k2 j3k0 j3k1 j3k2

  float4 own[2];
  int ms[2];
  if (kw == 0) {
    own[0] = acc[0]; own[1] = acc[1];
    ms[0] = smp[0];  ms[1] = smp[1];
  } else {
    own[0] = acc[2]; own[1] = acc[3];
    ms[0] = smp[2];  ms[1] = smp[3];
  }
  const int mys = 2 * kw;                  // LDS base (runtime ok)

  float p[2][OUT_DIM];
#pragma unroll
  for (int i = 0; i < 2; ++i) {
    const float4 pr = *(const float4*)&xch[g][mys + i][lane][0];
    const float h0 = fmaxf(own[i].x + pr.x, 0.f);
    const float h1 = fmaxf(own[i].y + pr.y, 0.f);
    const float h2 = fmaxf(own[i].z + pr.z, 0.f);
    const float h3 = fmaxf(own[i].w + pr.w, 0.f);
    p[i][0] = fmaf(h0, w2a.x, fmaf(h1, w2a.w, fmaf(h2, w2b.z, h3 * w2c.y)));
    p[i][1] = fmaf(h0, w2a.y, fmaf(h1, w2b.x, fmaf(h2, w2b.w, h3 * w2c.z)));
    p[i][2] = fmaf(h0, w2a.z, fmaf(h1, w2b.y, fmaf(h2, w2c.x, h3 * w2c.w)));
  }
#pragma unroll
  for (int off = 32; off > 0; off >>= 1)
#pragma unroll
    for (int i = 0; i < 2; ++i) {
      p[i][0] += __shfl_down(p[i][0], off);
      p[i][1] += __shfl_down(p[i][1], off);
      p[i][2] += __shfl_down(p[i][2], off);
    }

  if (lane == 0) {
    const float g0 = b2[a * OUT_DIM + 0];
    const float g1 = b2[a * OUT_DIM + 1];
    const float g2 = b2[a * OUT_DIM + 2];
#pragma unroll
    for (int i = 0; i < 2; ++i) {
      if (ms[i] >= 0) {
        float* o = out + (size_t)ms[i] * OUT_DIM;
        o[0] = p[i][0] + g0;
        o[1] = p[i][1] + g1;
        o[2] = p[i][2] + g2;
      }
    }
  }
}

// ---------------------------------------------------------------------------
extern "C" void kernel_launch(void* const* d_in, const int* in_sizes, int n_in,
                              void* d_out, int out_size, void* d_ws, size_t ws_size,
                              hipStream_t stream) {
  const int*   ids    = (const int*)d_in[0];
  const int*   aspect = (const int*)d_in[1];
  const float* emb    = (const float*)d_in[2];
  const float* W1     = (const float*)d_in[3];
  const float* b1     = (const float*)d_in[4];
  const float* W2     = (const float*)d_in[5];
  const float* b2     = (const float*)d_in[6];
  float*       out    = (float*)d_out;

  const int B     = in_sizes[1];
  const int nemb  = in_sizes[2];               // 15,000,000
  const int nblk  = (B + TILE - 1) / TILE + N_ASPECTS;
  const int nperm = nblk * TILE;               // multiple of 32 (and of MTILE)

  // workspace: [x: B*300 f32][perm: nperm i32][emb16: nemb bf16]
  float* x    = (float*)d_ws;
  int*   perm = (int*)((char*)d_ws + (size_t)B * EMB_DIM * sizeof(float));
  unsigned short* emb16 =
      (unsigned short*)((char*)perm + (((size_t)nperm * 4 + 15) & ~(size_t)15));

  prep_kernel<<<513, 1024, 0, stream>>>(emb, (unsigned int*)emb16, nemb / 8,
                                        aspect, B, perm, nperm);
  pool_kernel<<<(B + 3) / 4, 256, 0, stream>>>(ids, emb16, x, B);
  mlp_kernel<<<nperm / MTILE, 256, 0, stream>>>(x, aspect, perm, W1, b1, W2, b2, out);
}

// Round 13
// 129.354 us; speedup vs baseline: 1.1581x; 1.1581x over previous
//
#include <hip/hip_runtime.h>

constexpr int EMB_DIM   = 300;
constexpr int HIDDEN    = 256;
constexpr int OUT_DIM   = 3;
constexpr int SEQ       = 128;
constexpr int N_ASPECTS = 8;
constexpr int TILE      = 32;    // bucket padding granularity
constexpr int MTILE     = 8;     // samples per MLP block (2 groups x 4)

// ---------------------------------------------------------------------------
// bf16 helpers (RNE)
// ---------------------------------------------------------------------------
__device__ __forceinline__ unsigned int bfbits(float f) {
  unsigned int u = __float_as_uint(f);
  return (u + 0x7fffu + ((u >> 16) & 1u)) >> 16;
}
__device__ __forceinline__ unsigned int pack2(float lo, float hi) {
  return bfbits(lo) | (bfbits(hi) << 16);
}
__device__ __forceinline__ float blo(unsigned int u) { return __uint_as_float(u << 16); }
__device__ __forceinline__ float bhi(unsigned int u) { return __uint_as_float(u & 0xffff0000u); }

// ---------------------------------------------------------------------------
// Fused prep: block 0 = deterministic counting-sort bucketing (pad to TILE,
// -1 = padding); blocks 1..N = fp32->bf16 conversion of BOTH the embedding
// table (90 MB stream) and W1 (2.4 MB) in one grid-stride range.
// ---------------------------------------------------------------------------
__global__ __launch_bounds__(1024) void prep_kernel(
    const float* __restrict__ emb, unsigned int* __restrict__ emb16, int n8,
    const float* __restrict__ W1, unsigned int* __restrict__ w16, int nw8,
    const int* __restrict__ aspect, int B, int* __restrict__ perm, int nperm) {
  const int t = threadIdx.x;

  if (blockIdx.x != 0) {
    int i = (blockIdx.x - 1) * 1024 + t;
    const int stride = (gridDim.x - 1) * 1024;
    const int total8 = n8 + nw8;
    for (; i < total8; i += stride) {
      const float4* p;
      unsigned int* dst;
      int k;
      if (i < n8) { p = (const float4*)emb + (size_t)i * 2;        dst = emb16; k = i; }
      else        { p = (const float4*)W1  + (size_t)(i - n8) * 2; dst = w16;   k = i - n8; }
      float4 a = p[0], b = p[1];
      uint4 o;
      o.x = pack2(a.x, a.y); o.y = pack2(a.z, a.w);
      o.z = pack2(b.x, b.y); o.w = pack2(b.z, b.w);
      ((uint4*)dst)[k] = o;
    }
    return;
  }

  const int lane = t & 63, wave = t >> 6;          // 16 waves
  __shared__ int wcnt[16][N_ASPECTS];
  __shared__ int cur[16][N_ASPECTS];

  for (int i = t; i < nperm; i += 1024) perm[i] = -1;

  int my_a[8];
  int cnt[N_ASPECTS];
#pragma unroll
  for (int q = 0; q < N_ASPECTS; ++q) cnt[q] = 0;
#pragma unroll
  for (int k = 0; k < 8; ++k) {
    int s = t + k * 1024;
    int a = (s < B) ? aspect[s] : -1;
    my_a[k] = a;
#pragma unroll
    for (int q = 0; q < N_ASPECTS; ++q) cnt[q] += (a == q);
  }
#pragma unroll
  for (int q = 0; q < N_ASPECTS; ++q) {
    int c = cnt[q];
    for (int off = 32; off > 0; off >>= 1) c += __shfl_down(c, off);
    if (lane == 0) wcnt[wave][q] = c;
  }
  __syncthreads();
  if (t == 0) {
    int base = 0;
    for (int q = 0; q < N_ASPECTS; ++q) {
      int tot = 0;
      for (int w = 0; w < 16; ++w) { cur[w][q] = base + tot; tot += wcnt[w][q]; }
      base += ((tot + TILE - 1) / TILE) * TILE;
    }
  }
  __syncthreads();

#pragma unroll
  for (int k = 0; k < 8; ++k) {
    int a = my_a[k];
    int s = t + k * 1024;
#pragma unroll
    for (int q = 0; q < N_ASPECTS; ++q) {
      unsigned long long m = __ballot(a == q);
      if (a == q) {
        int rank = __popcll(m & ((1ull << lane) - 1ull));
        int pos = cur[wave][q] + rank;
        perm[pos] = s;
        if (rank == __popcll(m) - 1) cur[wave][q] = pos + 1;
      }
    }
  }
}

// ---------------------------------------------------------------------------
// Pool (R6/R10 best-measured form, FROZEN): one sample per wave; bitonic-
// sorted ids -> vocab-sweep convoy (L2-resident window). uint2 bf16 loads.
// ---------------------------------------------------------------------------
__global__ __launch_bounds__(256) void pool_kernel(
    const int* __restrict__ ids, const unsigned short* __restrict__ emb16,
    float* __restrict__ x, int B) {
  const int wave = threadIdx.x >> 6, lane = threadIdx.x & 63;
  const int b = blockIdx.x * 4 + wave;
  if (b >= B) return;

  int r0 = ids[(size_t)b * SEQ + lane];
  int r1 = ids[(size_t)b * SEQ + lane + 64];

#pragma unroll
  for (int k = 2; k <= 128; k <<= 1) {
#pragma unroll
    for (int j = k >> 1; j >= 1; j >>= 1) {
      if (j == 64) {
        int lo = min(r0, r1), hi = max(r0, r1);
        r0 = lo; r1 = hi;
      } else {
        const bool up0 = ((lane & k) == 0);
        const bool up1 = (((lane + 64) & k) == 0);
        const bool side = ((lane & j) == 0);
        int o0 = __shfl_xor(r0, j);
        int o1 = __shfl_xor(r1, j);
        r0 = (side == up0) ? min(r0, o0) : max(r0, o0);
        r1 = (side == up1) ? min(r1, o1) : max(r1, o1);
      }
    }
  }

  __shared__ int sid[4][SEQ];
  sid[wave][lane]      = r0;
  sid[wave][lane + 64] = r1;
  __syncthreads();

  float a0 = 0.f, a1 = 0.f, a2 = 0.f, a3 = 0.f;
  float c0 = 0.f, c1 = 0.f, c2 = 0.f, c3 = 0.f;
#pragma unroll 4
  for (int s = 0; s < SEQ; ++s) {
    const uint2* __restrict__ r =
        (const uint2*)(emb16 + (size_t)sid[wave][s] * EMB_DIM);
    uint2 v = r[lane];
    a0 += blo(v.x); a1 += bhi(v.x); a2 += blo(v.y); a3 += bhi(v.y);
    if (lane < 11) {
      uint2 w = r[64 + lane];
      c0 += blo(w.x); c1 += bhi(w.x); c2 += blo(w.y); c3 += bhi(w.y);
    }
  }
  const float sc = 1.0f / (float)SEQ;
  float4* __restrict__ xr = (float4*)(x + (size_t)b * EMB_DIM);
  xr[lane] = make_float4(a0 * sc, a1 * sc, a2 * sc, a3 * sc);
  if (lane < 11)
    xr[64 + lane] = make_float4(c0 * sc, c1 * sc, c2 * sc, c3 * sc);
}

// ---------------------------------------------------------------------------
// Routed MLP, split-K, MTILE=8 (R10 form) with BF16 W1: per d each lane loads
// uint2 = 4 bf16 cols (halves W1 L2 traffic 630->315 MB). All register-array
// indices compile-time static (rule #20).
// ---------------------------------------------------------------------------
__global__ __launch_bounds__(256) void mlp_kernel(
    const float* __restrict__ x, const int* __restrict__ aspect,
    const int* __restrict__ perm,
    const unsigned short* __restrict__ w16, const float* __restrict__ b1,
    const float* __restrict__ W2, const float* __restrict__ b2,
    float* __restrict__ out) {
  const int t = threadIdx.x;
  const int wave = t >> 6, lane = t & 63;
  const int g = wave >> 1;                 // sample group 0/1
  const int kw = wave & 1;                 // K-half
  const int start = blockIdx.x * MTILE;

  __shared__ int ss[MTILE];
  __shared__ float xch[2][4][64][4];       // partner-half partials, 8 KB

  if (t < MTILE) ss[t] = perm[start + t];
  __syncthreads();
  const int s0 = ss[0];
  if (s0 < 0) return;                      // fully-padded block (uniform exit)
  const int a = aspect[s0];

  int smp[4];
  const float* xrow[4];
#pragma unroll
  for (int s = 0; s < 4; ++s) {
    int m = __builtin_amdgcn_readfirstlane(ss[g * 4 + s]);
    smp[s] = m;
    xrow[s] = x + (size_t)(m < 0 ? s0 : m) * EMB_DIM;
  }

  // bf16 W1: lane covers cols 4*lane..4*lane+3 of each row d
  const unsigned short* __restrict__ w1r =
      w16 + (size_t)a * EMB_DIM * HIDDEN + 4 * lane;
  float4 acc[4];
  if (kw == 0) {
    const float4 bb = ((const float4*)(b1 + a * HIDDEN))[lane];
#pragma unroll
    for (int s = 0; s < 4; ++s) acc[s] = bb;
  } else {
#pragma unroll
    for (int s = 0; s < 4; ++s) acc[s] = make_float4(0.f, 0.f, 0.f, 0.f);
  }
  const int d0 = kw ? 160 : 0;
  const int d1 = kw ? EMB_DIM : 160;
#pragma unroll 2
  for (int d = d0; d < d1; d += 4) {
    float4 xv[4];
#pragma unroll
    for (int s = 0; s < 4; ++s) xv[s] = *(const float4*)(xrow[s] + d);
#pragma unroll
    for (int dd = 0; dd < 4; ++dd) {
      const uint2 wv = *(const uint2*)(w1r + (size_t)(d + dd) * HIDDEN);
      const float w0 = blo(wv.x), w1v = bhi(wv.x);
      const float w2v = blo(wv.y), w3v = bhi(wv.y);
#pragma unroll
      for (int s = 0; s < 4; ++s) {
        const float xs = dd == 0 ? xv[s].x : dd == 1 ? xv[s].y
                        : dd == 2 ? xv[s].z : xv[s].w;
        acc[s].x = fmaf(xs, w0,  acc[s].x);
        acc[s].y = fmaf(xs, w1v, acc[s].y);
        acc[s].z = fmaf(xs, w2v, acc[s].z);
        acc[s].w = fmaf(xs, w3v, acc[s].w);
      }
    }
  }

  if (kw == 0) {
    *(float4*)&xch[g][2][lane][0] = acc[2];
    *(float4*)&xch[g][3][lane][0] = acc[3];
  } else {
    *(float4*)&xch[g][0][lane][0] = acc[0];
    *(float4*)&xch[g][1][lane][0] = acc[1];
  }
  __syncthreads();

  const float4* __restrict__ w2p =
      (const float4*)(W2 + (size_t)a * HIDDEN * OUT_DIM + lane * 12);
  const float4 w2a = w2p[0];   // j0k0 j0k1 j0k2 j1k0
  const float4 w2b = w2p[1];   // j1k1 j1k2 j2k0 j2k1
  const float4 w2c = w2p[2];   // j2k2 j3k0 j3k1 j3k2

  float4 own[2];
  int ms[2];
  if (kw == 0) {
    own[0] = acc[0]; own[1] = acc[1];
    ms[0] = smp[0];  ms[1] = smp[1];
  } else {
    own[0] = acc[2]; own[1] = acc[3];
    ms[0] = smp[2];  ms[1] = smp[3];
  }
  const int mys = 2 * kw;                  // LDS base (runtime ok)

  float p[2][OUT_DIM];
#pragma unroll
  for (int i = 0; i < 2; ++i) {
    const float4 pr = *(const float4*)&xch[g][mys + i][lane][0];
    const float h0 = fmaxf(own[i].x + pr.x, 0.f);
    const float h1 = fmaxf(own[i].y + pr.y, 0.f);
    const float h2 = fmaxf(own[i].z + pr.z, 0.f);
    const float h3 = fmaxf(own[i].w + pr.w, 0.f);
    p[i][0] = fmaf(h0, w2a.x, fmaf(h1, w2a.w, fmaf(h2, w2b.z, h3 * w2c.y)));
    p[i][1] = fmaf(h0, w2a.y, fmaf(h1, w2b.x, fmaf(h2, w2b.w, h3 * w2c.z)));
    p[i][2] = fmaf(h0, w2a.z, fmaf(h1, w2b.y, fmaf(h2, w2c.x, h3 * w2c.w)));
  }
#pragma unroll
  for (int off = 32; off > 0; off >>= 1)
#pragma unroll
    for (int i = 0; i < 2; ++i) {
      p[i][0] += __shfl_down(p[i][0], off);
      p[i][1] += __shfl_down(p[i][1], off);
      p[i][2] += __shfl_down(p[i][2], off);
    }

  if (lane == 0) {
    const float g0 = b2[a * OUT_DIM + 0];
    const float g1 = b2[a * OUT_DIM + 1];
    const float g2 = b2[a * OUT_DIM + 2];
#pragma unroll
    for (int i = 0; i < 2; ++i) {
      if (ms[i] >= 0) {
        float* o = out + (size_t)ms[i] * OUT_DIM;
        o[0] = p[i][0] + g0;
        o[1] = p[i][1] + g1;
        o[2] = p[i][2] + g2;
      }
    }
  }
}

// ---------------------------------------------------------------------------
extern "C" void kernel_launch(void* const* d_in, const int* in_sizes, int n_in,
                              void* d_out, int out_size, void* d_ws, size_t ws_size,
                              hipStream_t stream) {
  const int*   ids    = (const int*)d_in[0];
  const int*   aspect = (const int*)d_in[1];
  const float* emb    = (const float*)d_in[2];
  const float* W1     = (const float*)d_in[3];
  const float* b1     = (const float*)d_in[4];
  const float* W2     = (const float*)d_in[5];
  const float* b2     = (const float*)d_in[6];
  float*       out    = (float*)d_out;

  const int B     = in_sizes[1];
  const int nemb  = in_sizes[2];               // 15,000,000 (div by 8)
  const int nw1   = in_sizes[3];               // 614,400 (div by 8)
  const int nblk  = (B + TILE - 1) / TILE + N_ASPECTS;
  const int nperm = nblk * TILE;               // multiple of 32 (and of MTILE)

  // workspace: [x: B*300 f32][perm: nperm i32][emb16: nemb bf16][w16: nw1 bf16]
  float* x    = (float*)d_ws;
  int*   perm = (int*)((char*)d_ws + (size_t)B * EMB_DIM * sizeof(float));
  unsigned short* emb16 =
      (unsigned short*)((char*)perm + (((size_t)nperm * 4 + 15) & ~(size_t)15));
  unsigned short* w16 = emb16 + (size_t)nemb;

  prep_kernel<<<513, 1024, 0, stream>>>(emb, (unsigned int*)emb16, nemb / 8,
                                        W1, (unsigned int*)w16, nw1 / 8,
                                        aspect, B, perm, nperm);
  pool_kernel<<<(B + 3) / 4, 256, 0, stream>>>(ids, emb16, x, B);
  mlp_kernel<<<nperm / MTILE, 256, 0, stream>>>(x, aspect, perm, w16, b1, W2, b2, out);
}

// Round 14
// 119.866 us; speedup vs baseline: 1.2497x; 1.0792x over previous
//
#include <hip/hip_runtime.h>

constexpr int EMB_DIM   = 300;
constexpr int HIDDEN    = 256;
constexpr int OUT_DIM   = 3;
constexpr int SEQ       = 128;
constexpr int N_ASPECTS = 8;
constexpr int TILE      = 32;    // bucket padding granularity (multiple of MTILE)
constexpr int MTILE     = 8;     // samples per fused block (4 waves x 2)

// ---------------------------------------------------------------------------
// bf16 helpers (RNE)
// ---------------------------------------------------------------------------
__device__ __forceinline__ unsigned int bfbits(float f) {
  unsigned int u = __float_as_uint(f);
  return (u + 0x7fffu + ((u >> 16) & 1u)) >> 16;
}
__device__ __forceinline__ unsigned int pack2(float lo, float hi) {
  return bfbits(lo) | (bfbits(hi) << 16);
}
__device__ __forceinline__ float blo(unsigned int u) { return __uint_as_float(u << 16); }
__device__ __forceinline__ float bhi(unsigned int u) { return __uint_as_float(u & 0xffff0000u); }

// ---------------------------------------------------------------------------
// Fused prep: block 0 = deterministic counting-sort bucketing (pad to TILE,
// -1 = padding); blocks 1..N = fp32->bf16 conversion of the embedding table
// (90 MB stream) and W1 (2.4 MB) in one grid-stride range.
// ---------------------------------------------------------------------------
__global__ __launch_bounds__(1024) void prep_kernel(
    const float* __restrict__ emb, unsigned int* __restrict__ emb16, int n8,
    const float* __restrict__ W1, unsigned int* __restrict__ w16, int nw8,
    const int* __restrict__ aspect, int B, int* __restrict__ perm, int nperm) {
  const int t = threadIdx.x;

  if (blockIdx.x != 0) {
    int i = (blockIdx.x - 1) * 1024 + t;
    const int stride = (gridDim.x - 1) * 1024;
    const int total8 = n8 + nw8;
    for (; i < total8; i += stride) {
      const float4* p;
      unsigned int* dst;
      int k;
      if (i < n8) { p = (const float4*)emb + (size_t)i * 2;        dst = emb16; k = i; }
      else        { p = (const float4*)W1  + (size_t)(i - n8) * 2; dst = w16;   k = i - n8; }
      float4 a = p[0], b = p[1];
      uint4 o;
      o.x = pack2(a.x, a.y); o.y = pack2(a.z, a.w);
      o.z = pack2(b.x, b.y); o.w = pack2(b.z, b.w);
      ((uint4*)dst)[k] = o;
    }
    return;
  }

  const int lane = t & 63, wave = t >> 6;          // 16 waves
  __shared__ int wcnt[16][N_ASPECTS];
  __shared__ int cur[16][N_ASPECTS];

  for (int i = t; i < nperm; i += 1024) perm[i] = -1;

  int my_a[8];
  int cnt[N_ASPECTS];
#pragma unroll
  for (int q = 0; q < N_ASPECTS; ++q) cnt[q] = 0;
#pragma unroll
  for (int k = 0; k < 8; ++k) {
    int s = t + k * 1024;
    int a = (s < B) ? aspect[s] : -1;
    my_a[k] = a;
#pragma unroll
    for (int q = 0; q < N_ASPECTS; ++q) cnt[q] += (a == q);
  }
#pragma unroll
  for (int q = 0; q < N_ASPECTS; ++q) {
    int c = cnt[q];
    for (int off = 32; off > 0; off >>= 1) c += __shfl_down(c, off);
    if (lane == 0) wcnt[wave][q] = c;
  }
  __syncthreads();
  if (t == 0) {
    int base = 0;
    for (int q = 0; q < N_ASPECTS; ++q) {
      int tot = 0;
      for (int w = 0; w < 16; ++w) { cur[w][q] = base + tot; tot += wcnt[w][q]; }
      base += ((tot + TILE - 1) / TILE) * TILE;
    }
  }
  __syncthreads();

#pragma unroll
  for (int k = 0; k < 8; ++k) {
    int a = my_a[k];
    int s = t + k * 1024;
#pragma unroll
    for (int q = 0; q < N_ASPECTS; ++q) {
      unsigned long long m = __ballot(a == q);
      if (a == q) {
        int rank = __popcll(m & ((1ull << lane) - 1ull));
        int pos = cur[wave][q] + rank;
        perm[pos] = s;
        if (rank == __popcll(m) - 1) cur[wave][q] = pos + 1;
      }
    }
  }
}

// ---------------------------------------------------------------------------
// Fused pool+MLP: block = 8 bucketed same-aspect samples, 4 waves.
// Pool phase: wave w pools samples {2w, 2w+1} INTERLEAVED (2 sorted-id
// sweeps ping-pong -> 2x in-flight tokens per wave, compensating the halved
// wave count vs the standalone pool). Pooled x goes to LDS only.
// MLP phase (after one barrier): R13 split-K structure, x read from LDS,
// bf16 W1. All register-array indices compile-time static (rule #20).
// ---------------------------------------------------------------------------
__global__ __launch_bounds__(256) void fused_kernel(
    const int* __restrict__ ids, const unsigned short* __restrict__ emb16,
    const int* __restrict__ aspect, const int* __restrict__ perm,
    const unsigned short* __restrict__ w16, const float* __restrict__ b1,
    const float* __restrict__ W2, const float* __restrict__ b2,
    float* __restrict__ out) {
  const int t = threadIdx.x;
  const int wave = t >> 6, lane = t & 63;
  const int start = blockIdx.x * MTILE;

  __shared__ int   ss[MTILE];
  __shared__ int   sid[MTILE][SEQ];          // sorted token ids, 4 KB
  __shared__ float xs[MTILE][EMB_DIM + 4];   // pooled x rows (1216 B stride)
  __shared__ float xch[2][4][64][4];         // MLP partial exchange, 8 KB

  if (t < MTILE) ss[t] = perm[start + t];
  __syncthreads();
  const int s0 = ss[0];
  if (s0 < 0) return;                        // fully-padded block
  const int a = aspect[s0];

  // ---- pool phase: this wave's two samples ----
  const int sa = 2 * wave, sb = 2 * wave + 1;
  const int ma = __builtin_amdgcn_readfirstlane(ss[sa] < 0 ? s0 : ss[sa]);
  const int mb = __builtin_amdgcn_readfirstlane(ss[sb] < 0 ? s0 : ss[sb]);

  int r0 = ids[(size_t)ma * SEQ + lane];
  int r1 = ids[(size_t)ma * SEQ + lane + 64];
  int r2 = ids[(size_t)mb * SEQ + lane];
  int r3 = ids[(size_t)mb * SEQ + lane + 64];

  // two interleaved bitonic sorts (128 ids each); sort bugs can only cost
  // locality, never correctness (compare-exchange preserves the multiset)
#pragma unroll
  for (int k = 2; k <= 128; k <<= 1) {
#pragma unroll
    for (int j = k >> 1; j >= 1; j >>= 1) {
      if (j == 64) {
        int lo0 = min(r0, r1), hi0 = max(r0, r1);
        int lo1 = min(r2, r3), hi1 = max(r2, r3);
        r0 = lo0; r1 = hi0; r2 = lo1; r3 = hi1;
      } else {
        const bool up0 = ((lane & k) == 0);
        const bool up1 = (((lane + 64) & k) == 0);
        const bool side = ((lane & j) == 0);
        int o0 = __shfl_xor(r0, j);
        int o1 = __shfl_xor(r1, j);
        int o2 = __shfl_xor(r2, j);
        int o3 = __shfl_xor(r3, j);
        r0 = (side == up0) ? min(r0, o0) : max(r0, o0);
        r1 = (side == up1) ? min(r1, o1) : max(r1, o1);
        r2 = (side == up0) ? min(r2, o2) : max(r2, o2);
        r3 = (side == up1) ? min(r3, o3) : max(r3, o3);
      }
    }
  }

  sid[sa][lane]      = r0;
  sid[sa][lane + 64] = r1;
  sid[sb][lane]      = r2;
  sid[sb][lane + 64] = r3;
  // same-wave LDS RAW below: compiler inserts lgkmcnt waits; no barrier needed

  float p0 = 0.f, p1 = 0.f, p2 = 0.f, p3 = 0.f;   // sample a, dims 4l..
  float q0 = 0.f, q1 = 0.f, q2 = 0.f, q3 = 0.f;   // sample b, dims 4l..
  float ta0 = 0.f, ta1 = 0.f, ta2 = 0.f, ta3 = 0.f; // sample a tail
  float tb0 = 0.f, tb1 = 0.f, tb2 = 0.f, tb3 = 0.f; // sample b tail
  const bool tail = (lane < 11);

#pragma unroll 4
  for (int s = 0; s < SEQ; ++s) {
    const uint2* __restrict__ ra =
        (const uint2*)(emb16 + (size_t)sid[sa][s] * EMB_DIM);
    const uint2* __restrict__ rb =
        (const uint2*)(emb16 + (size_t)sid[sb][s] * EMB_DIM);
    uint2 va = ra[lane];
    uint2 vb = rb[lane];
    p0 += blo(va.x); p1 += bhi(va.x); p2 += blo(va.y); p3 += bhi(va.y);
    q0 += blo(vb.x); q1 += bhi(vb.x); q2 += blo(vb.y); q3 += bhi(vb.y);
    if (tail) {
      uint2 wa = ra[64 + lane];
      uint2 wb = rb[64 + lane];
      ta0 += blo(wa.x); ta1 += bhi(wa.x); ta2 += blo(wa.y); ta3 += bhi(wa.y);
      tb0 += blo(wb.x); tb1 += bhi(wb.x); tb2 += blo(wb.y); tb3 += bhi(wb.y);
    }
  }

  const float sc = 1.0f / (float)SEQ;
  *(float4*)&xs[sa][4 * lane] = make_float4(p0 * sc, p1 * sc, p2 * sc, p3 * sc);
  *(float4*)&xs[sb][4 * lane] = make_float4(q0 * sc, q1 * sc, q2 * sc, q3 * sc);
  if (tail) {
    *(float4*)&xs[sa][256 + 4 * lane] =
        make_float4(ta0 * sc, ta1 * sc, ta2 * sc, ta3 * sc);
    *(float4*)&xs[sb][256 + 4 * lane] =
        make_float4(tb0 * sc, tb1 * sc, tb2 * sc, tb3 * sc);
  }
  __syncthreads();

  // ---- MLP phase (R13 structure, x from LDS) ----
  const int g = wave >> 1;                 // sample group 0/1 (samples g*4..)
  const int kw = wave & 1;                 // K-half

  int smp[4];
#pragma unroll
  for (int s = 0; s < 4; ++s)
    smp[s] = __builtin_amdgcn_readfirstlane(ss[g * 4 + s]);

  const unsigned short* __restrict__ w1r =
      w16 + (size_t)a * EMB_DIM * HIDDEN + 4 * lane;
  float4 acc[4];
  if (kw == 0) {
    const float4 bb = ((const float4*)(b1 + a * HIDDEN))[lane];
#pragma unroll
    for (int s = 0; s < 4; ++s) acc[s] = bb;
  } else {
#pragma unroll
    for (int s = 0; s < 4; ++s) acc[s] = make_float4(0.f, 0.f, 0.f, 0.f);
  }
  const int d0 = kw ? 160 : 0;
  const int d1 = kw ? EMB_DIM : 160;
#pragma unroll 2
  for (int d = d0; d < d1; d += 4) {
    float4 xv[4];
#pragma unroll
    for (int s = 0; s < 4; ++s) xv[s] = *(const float4*)&xs[g * 4 + s][d];
#pragma unroll
    for (int dd = 0; dd < 4; ++dd) {
      const uint2 wv = *(const uint2*)(w1r + (size_t)(d + dd) * HIDDEN);
      const float w0 = blo(wv.x), w1v = bhi(wv.x);
      const float w2v = blo(wv.y), w3v = bhi(wv.y);
#pragma unroll
      for (int s = 0; s < 4; ++s) {
        const float xsc = dd == 0 ? xv[s].x : dd == 1 ? xv[s].y
                         : dd == 2 ? xv[s].z : xv[s].w;
        acc[s].x = fmaf(xsc, w0,  acc[s].x);
        acc[s].y = fmaf(xsc, w1v, acc[s].y);
        acc[s].z = fmaf(xsc, w2v, acc[s].z);
        acc[s].w = fmaf(xsc, w3v, acc[s].w);
      }
    }
  }

  if (kw == 0) {
    *(float4*)&xch[g][2][lane][0] = acc[2];
    *(float4*)&xch[g][3][lane][0] = acc[3];
  } else {
    *(float4*)&xch[g][0][lane][0] = acc[0];
    *(float4*)&xch[g][1][lane][0] = acc[1];
  }
  __syncthreads();

  const float4* __restrict__ w2p =
      (const float4*)(W2 + (size_t)a * HIDDEN * OUT_DIM + lane * 12);
  const float4 w2a = w2p[0];   // j0k0 j0k1 j0k2 j1k0
  const float4 w2b = w2p[1];   // j1k1 j1k2 j2k0 j2k1
  const float4 w2c = w2p[2];   // j2k2 j3k0 j3k1 j3k2

  float4 own[2];
  int ms[2];
  if (kw == 0) {
    own[0] = acc[0]; own[1] = acc[1];
    ms[0] = smp[0];  ms[1] = smp[1];
  } else {
    own[0] = acc[2]; own[1] = acc[3];
    ms[0] = smp[2];  ms[1] = smp[3];
  }
  const int mys = 2 * kw;                  // LDS base (runtime ok)

  float pp[2][OUT_DIM];
#pragma unroll
  for (int i = 0; i < 2; ++i) {
    const float4 pr = *(const float4*)&xch[g][mys + i][lane][0];
    const float h0 = fmaxf(own[i].x + pr.x, 0.f);
    const float h1 = fmaxf(own[i].y + pr.y, 0.f);
    const float h2 = fmaxf(own[i].z + pr.z, 0.f);
    const float h3 = fmaxf(own[i].w + pr.w, 0.f);
    pp[i][0] = fmaf(h0, w2a.x, fmaf(h1, w2a.w, fmaf(h2, w2b.z, h3 * w2c.y)));
    pp[i][1] = fmaf(h0, w2a.y, fmaf(h1, w2b.x, fmaf(h2, w2b.w, h3 * w2c.z)));
    pp[i][2] = fmaf(h0, w2a.z, fmaf(h1, w2b.y, fmaf(h2, w2c.x, h3 * w2c.w)));
  }
#pragma unroll
  for (int off = 32; off > 0; off >>= 1)
#pragma unroll
    for (int i = 0; i < 2; ++i) {
      pp[i][0] += __shfl_down(pp[i][0], off);
      pp[i][1] += __shfl_down(pp[i][1], off);
      pp[i][2] += __shfl_down(pp[i][2], off);
    }

  if (lane == 0) {
    const float g0 = b2[a * OUT_DIM + 0];
    const float g1 = b2[a * OUT_DIM + 1];
    const float g2 = b2[a * OUT_DIM + 2];
#pragma unroll
    for (int i = 0; i < 2; ++i) {
      if (ms[i] >= 0) {
        float* o = out + (size_t)ms[i] * OUT_DIM;
        o[0] = pp[i][0] + g0;
        o[1] = pp[i][1] + g1;
        o[2] = pp[i][2] + g2;
      }
    }
  }
}

// ---------------------------------------------------------------------------
extern "C" void kernel_launch(void* const* d_in, const int* in_sizes, int n_in,
                              void* d_out, int out_size, void* d_ws, size_t ws_size,
                              hipStream_t stream) {
  const int*   ids    = (const int*)d_in[0];
  const int*   aspect = (const int*)d_in[1];
  const float* emb    = (const float*)d_in[2];
  const float* W1     = (const float*)d_in[3];
  const float* b1     = (const float*)d_in[4];
  const float* W2     = (const float*)d_in[5];
  const float* b2     = (const float*)d_in[6];
  float*       out    = (float*)d_out;

  const int B     = in_sizes[1];
  const int nemb  = in_sizes[2];               // 15,000,000 (div by 8)
  const int nw1   = in_sizes[3];               // 614,400 (div by 8)
  const int nblk  = (B + TILE - 1) / TILE + N_ASPECTS;
  const int nperm = nblk * TILE;               // multiple of 32 (and of MTILE)

  // workspace: [perm: nperm i32][emb16: nemb bf16][w16: nw1 bf16]
  int* perm = (int*)d_ws;
  unsigned short* emb16 =
      (unsigned short*)((char*)perm + (((size_t)nperm * 4 + 15) & ~(size_t)15));
  unsigned short* w16 = emb16 + (size_t)nemb;

  prep_kernel<<<513, 1024, 0, stream>>>(emb, (unsigned int*)emb16, nemb / 8,
                                        W1, (unsigned int*)w16, nw1 / 8,
                                        aspect, B, perm, nperm);
  fused_kernel<<<nperm / MTILE, 256, 0, stream>>>(ids, emb16, aspect, perm,
                                                  w16, b1, W2, b2, out);
}